// Round 3
// baseline (460.041 us; speedup 1.0000x reference)
//
#include <hip/hip_runtime.h>
#include <hip/hip_bf16.h>

typedef __attribute__((ext_vector_type(8))) short bf16x8;   // 8 bf16 = 4 VGPRs (guide §3)
typedef __attribute__((ext_vector_type(4))) float f32x4;
typedef unsigned short u16t;

#define DEVINL static __device__ __forceinline__

DEVINL u16t f2bf(float f) {
  union { __hip_bfloat16 h; u16t u; } cv;
  cv.h = __float2bfloat16(f);
  return cv.u;
}

// ---------------------------------------------------------------------------
// Input dtype detector. If x is fp32, even u16 positions are low-mantissa
// halves -> ~22% decode as bf16 with exponent field >= 200 (|v| > 2^72).
// If x is genuine bf16 N(0,1) data, none do. flag: 0 = fp32, 1 = bf16.
// ---------------------------------------------------------------------------
__global__ void detect_dtype(const u16t* __restrict__ x, int* __restrict__ flag) {
  const int i = threadIdx.x;                 // 64 threads, 1 block
  const u16t u = x[i * 2];                   // even positions only
  int hit = (((u >> 7) & 0xFF) >= 200) ? 1 : 0;
  #pragma unroll
  for (int m = 1; m < 64; m <<= 1) hit += __shfl_xor(hit, m, 64);
  if (i == 0) *flag = (hit >= 4) ? 0 : 1;
}

// Load 8 consecutive elements (bf16 or fp32 per isbf) as a bf16x8 fragment.
// idx is the ELEMENT index; base is a byte pointer.
DEVINL bf16x8 load8_dyn(const char* base, size_t idx, int isbf) {
  if (isbf) return *(const bf16x8*)(base + idx * 2);
  const float* f = (const float*)(base + idx * 4);
  const float4 a = *(const float4*)f;
  const float4 b = *(const float4*)(f + 4);
  bf16x8 r;
  r[0] = (short)f2bf(a.x); r[1] = (short)f2bf(a.y);
  r[2] = (short)f2bf(a.z); r[3] = (short)f2bf(a.w);
  r[4] = (short)f2bf(b.x); r[5] = (short)f2bf(b.y);
  r[6] = (short)f2bf(b.z); r[7] = (short)f2bf(b.w);
  return r;
}

// ---------------------------------------------------------------------------
// C[m,n] = sum_k A[m,k]*B[n,k].  A:[M,K], B:[N,K] row-major.
// ADYN/BDYN: operand dtype follows *flagp (fp32 or bf16); false = bf16 always.
// MODE 0: C row-major [M,N], stored fp32 if *flagp==0 else bf16.
// MODE 1: head-split bf16 store C[((b*16+h)*2048+t)*64+d], b=m>>11,t=m&2047,
//         h=n>>6,d=n&63.
// ---------------------------------------------------------------------------
template <int MODE, bool ADYN, bool BDYN>
__global__ __launch_bounds__(256) void gemm_bt(
    const void* __restrict__ A,
    const void* __restrict__ B0, const void* __restrict__ B1, const void* __restrict__ B2,
    void* __restrict__ C0, void* __restrict__ C1, void* __restrict__ C2,
    int M, int N, int K, const int* __restrict__ flagp) {
  __shared__ u16t As[128 * 32];
  __shared__ u16t Bs[128 * 32];

  const void* B = B0;
  void* C = C0;
  if (blockIdx.z == 1) { B = B1; C = C1; }
  else if (blockIdx.z == 2) { B = B2; C = C2; }

  const int fl = *flagp;              // 1 = inputs bf16, 0 = inputs fp32
  const int abf = ADYN ? fl : 1;
  const int bbf = BDYN ? fl : 1;

  const int tid = threadIdx.x;
  const int lane = tid & 63;
  const int w = tid >> 6;
  const int wm = w >> 1, wn = w & 1;
  const int quad = lane >> 4, cl = lane & 15;
  const int m0 = blockIdx.y * 128;
  const int n0 = blockIdx.x * 128;

  f32x4 acc[4][4] = {};

  for (int k0 = 0; k0 < K; k0 += 32) {
    __syncthreads();                 // previous iteration's fragment reads complete
    bf16x8 va[2], vb[2];
    int rowv[2], colv[2];
    #pragma unroll
    for (int i = 0; i < 2; ++i) {
      const int e = i * 256 + tid;   // 0..511 8-elem chunks (128 rows x 4 chunks)
      rowv[i] = e >> 2;
      colv[i] = (e & 3) * 8;
      va[i] = load8_dyn((const char*)A, (size_t)(m0 + rowv[i]) * K + k0 + colv[i], abf);
      vb[i] = load8_dyn((const char*)B, (size_t)(n0 + rowv[i]) * K + k0 + colv[i], bbf);
    }
    #pragma unroll
    for (int i = 0; i < 2; ++i) {
      *(bf16x8*)&As[rowv[i] * 32 + colv[i]] = va[i];
      *(bf16x8*)&Bs[rowv[i] * 32 + colv[i]] = vb[i];
    }
    __syncthreads();                 // staging visible to all waves
    bf16x8 af[4], bfr[4];
    #pragma unroll
    for (int i = 0; i < 4; ++i)
      af[i] = *(const bf16x8*)&As[(wm * 64 + i * 16 + cl) * 32 + quad * 8];
    #pragma unroll
    for (int j = 0; j < 4; ++j)
      bfr[j] = *(const bf16x8*)&Bs[(wn * 64 + j * 16 + cl) * 32 + quad * 8];
    #pragma unroll
    for (int i = 0; i < 4; ++i)
      #pragma unroll
      for (int j = 0; j < 4; ++j)
        acc[i][j] = __builtin_amdgcn_mfma_f32_16x16x32_bf16(af[i], bfr[j], acc[i][j], 0, 0, 0);
  }

  #pragma unroll
  for (int i = 0; i < 4; ++i)
    #pragma unroll
    for (int j = 0; j < 4; ++j)
      #pragma unroll
      for (int r = 0; r < 4; ++r) {
        const int m = m0 + wm * 64 + i * 16 + quad * 4 + r;  // C/D: row=quad*4+reg
        const int n = n0 + wn * 64 + j * 16 + cl;            //      col=lane&15
        const float v = acc[i][j][r];
        if (MODE == 0) {
          if (fl) ((u16t*)C)[(size_t)m * N + n] = f2bf(v);
          else    ((float*)C)[(size_t)m * N + n] = v;
        } else {
          const int b = m >> 11, t = m & 2047, h = n >> 6, d = n & 63;
          ((u16t*)C)[(((size_t)(b * 16 + h)) * 2048 + t) * 64 + d] = f2bf(v);
        }
      }
}

// ---------------------------------------------------------------------------
// Flash attention. Grid: (T/64 q-tiles, B*H). Block 256 = 4 waves; wave owns
// 16 q-rows. Q,K,V: [bh][2048][64] bf16. Y out: token-major [4096][1024] bf16.
// ---------------------------------------------------------------------------
__global__ __launch_bounds__(256) void flash_attn(
    const u16t* __restrict__ Q, const u16t* __restrict__ K,
    const u16t* __restrict__ V, u16t* __restrict__ Y) {
  __shared__ u16t Ks[128 * 72];       // K-tile, rows padded 64->72
  __shared__ u16t Vt[64 * 136];       // V-tile transposed: Vt[d][j], 128->136
  __shared__ u16t Ps[4 * 16 * 136];   // per-wave P, C-layout -> A-layout roundtrip

  const int tid = threadIdx.x;
  const int lane = tid & 63;
  const int w = tid >> 6;
  const int quad = lane >> 4, cl = lane & 15;
  const int bh = blockIdx.y;
  const int q0 = blockIdx.x * 64;
  const size_t base = (size_t)bh * 2048 * 64;

  // Q A-fragments are tile-invariant: registers (A[m=lane&15][k=quad*8+j])
  bf16x8 aq[2];
  #pragma unroll
  for (int ks = 0; ks < 2; ++ks)
    aq[ks] = *(const bf16x8*)&Q[base + (size_t)(q0 + w * 16 + cl) * 64 + ks * 32 + quad * 8];

  f32x4 o[4] = {};                    // O acc (C-layout): row=quad*4+r, col=ds*16+cl
  float mrow[4], lrow[4];
  #pragma unroll
  for (int r = 0; r < 4; ++r) { mrow[r] = -1e30f; lrow[r] = 0.f; }

  u16t* Pw = &Ps[w * 16 * 136];

  for (int j0 = 0; j0 < 2048; j0 += 128) {
    __syncthreads();                  // previous tile fully consumed
    #pragma unroll
    for (int i = 0; i < 4; ++i) {
      const int idx = i * 256 + tid;  // 0..1023 16B-chunks
      const int r = idx >> 3, c = idx & 7;
      *(float4*)&Ks[r * 72 + c * 8] = *(const float4*)&K[base + (size_t)(j0 + r) * 64 + c * 8];
    }
    #pragma unroll
    for (int i = 0; i < 32; ++i) {
      const int e = i * 256 + tid;    // 0..8191: Vt[d][j] = V[j0+j][d]
      const int d = e >> 7, j = e & 127;
      Vt[d * 136 + j] = V[base + (size_t)(j0 + j) * 64 + d];
    }
    __syncthreads();

    // S = Q K^T, *1/sqrt(64)
    f32x4 s[8] = {};
    #pragma unroll
    for (int ks = 0; ks < 2; ++ks)
      #pragma unroll
      for (int js = 0; js < 8; ++js) {
        const bf16x8 bk = *(const bf16x8*)&Ks[(js * 16 + cl) * 72 + ks * 32 + quad * 8];
        s[js] = __builtin_amdgcn_mfma_f32_16x16x32_bf16(aq[ks], bk, s[js], 0, 0, 0);
      }
    #pragma unroll
    for (int js = 0; js < 8; ++js)
      #pragma unroll
      for (int r = 0; r < 4; ++r) s[js][r] *= 0.125f;

    // online softmax; row (quad*4+r) owned by the 16 consecutive lanes of quad
    float mnew[4], alpha[4];
    #pragma unroll
    for (int r = 0; r < 4; ++r) {
      float v = s[0][r];
      #pragma unroll
      for (int js = 1; js < 8; ++js) v = fmaxf(v, s[js][r]);
      #pragma unroll
      for (int msk = 1; msk < 16; msk <<= 1) v = fmaxf(v, __shfl_xor(v, msk, 64));
      mnew[r] = fmaxf(mrow[r], v);
      alpha[r] = __expf(mrow[r] - mnew[r]);
      mrow[r] = mnew[r];
    }
    float rsum[4] = {0.f, 0.f, 0.f, 0.f};
    #pragma unroll
    for (int js = 0; js < 8; ++js)
      #pragma unroll
      for (int r = 0; r < 4; ++r) {
        const float p = __expf(s[js][r] - mnew[r]);
        rsum[r] += p;
        Pw[(quad * 4 + r) * 136 + js * 16 + cl] = f2bf(p);   // C-layout scatter
      }
    #pragma unroll
    for (int r = 0; r < 4; ++r) {
      float v = rsum[r];
      #pragma unroll
      for (int msk = 1; msk < 16; msk <<= 1) v += __shfl_xor(v, msk, 64);
      lrow[r] = lrow[r] * alpha[r] + v;
      #pragma unroll
      for (int ds = 0; ds < 4; ++ds) o[ds][r] *= alpha[r];
    }
    // Pw is wave-private: same-wave LDS write->read needs only lgkmcnt (compiler)

    // O += P @ V  (A=P[m=cl][k=j], B=Vt[n=d][k=j]; 4 k-steps x 4 d-subtiles)
    #pragma unroll
    for (int ks = 0; ks < 4; ++ks) {
      const bf16x8 ap = *(const bf16x8*)&Pw[cl * 136 + ks * 32 + quad * 8];
      #pragma unroll
      for (int ds = 0; ds < 4; ++ds) {
        const bf16x8 bv = *(const bf16x8*)&Vt[(ds * 16 + cl) * 136 + ks * 32 + quad * 8];
        o[ds] = __builtin_amdgcn_mfma_f32_16x16x32_bf16(ap, bv, o[ds], 0, 0, 0);
      }
    }
  }

  const int b = bh >> 4, h = bh & 15;
  #pragma unroll
  for (int ds = 0; ds < 4; ++ds)
    #pragma unroll
    for (int r = 0; r < 4; ++r) {
      const int t = q0 + w * 16 + quad * 4 + r;
      const int d = ds * 16 + cl;
      Y[((size_t)b * 2048 + t) * 1024 + h * 64 + d] = f2bf(o[ds][r] / lrow[r]);
    }
}

extern "C" void kernel_launch(void* const* d_in, const int* in_sizes, int n_in,
                              void* d_out, int out_size, void* d_ws, size_t ws_size,
                              hipStream_t stream) {
  (void)in_sizes; (void)n_in; (void)out_size; (void)ws_size;
  const void* x  = d_in[0];
  const void* Wq = d_in[1];
  const void* Wk = d_in[2];
  const void* Wv = d_in[3];
  const void* Wo = d_in[4];

  char* ws = (char*)d_ws;
  int*  flag = (int*)ws;                                   // dtype flag
  u16t* Qw = (u16t*)(ws + (size_t)1  * 1024 * 1024);       // [32][2048][64] bf16
  u16t* Kw = (u16t*)(ws + (size_t)9  * 1024 * 1024);
  u16t* Vw = (u16t*)(ws + (size_t)17 * 1024 * 1024);
  u16t* Yw = (u16t*)(ws + (size_t)25 * 1024 * 1024);       // [4096][1024] bf16

  detect_dtype<<<1, 64, 0, stream>>>((const u16t*)x, flag);
  // Q/K/V = x @ W^T with head-split epilogue (grid.z selects weight)
  gemm_bt<1, true, true><<<dim3(8, 32, 3), 256, 0, stream>>>(
      x, Wq, Wk, Wv, Qw, Kw, Vw, 4096, 1024, 1024, flag);
  // fused softmax(QK^T/8) V
  flash_attn<<<dim3(32, 32), 256, 0, stream>>>(Qw, Kw, Vw, Yw);
  // out = Y @ Wo^T   (A = Yw is always bf16; B/out dtype follow flag)
  gemm_bt<0, false, true><<<dim3(8, 32, 1), 256, 0, stream>>>(
      Yw, Wo, Wo, Wo, d_out, d_out, d_out, 4096, 1024, 1024, flag);
}

// Round 4
// 293.307 us; speedup vs baseline: 1.5685x; 1.5685x over previous
//
#include <hip/hip_runtime.h>
#include <hip/hip_bf16.h>

typedef __attribute__((ext_vector_type(8))) short bf16x8;   // 8 bf16 = 4 VGPRs (guide §3)
typedef __attribute__((ext_vector_type(4))) float f32x4;
typedef unsigned short u16t;

#define DEVINL static __device__ __forceinline__

DEVINL u16t f2bf(float f) {
  union { __hip_bfloat16 h; u16t u; } cv;
  cv.h = __float2bfloat16(f);
  return cv.u;
}

// ---------------------------------------------------------------------------
// Input dtype detector (x may arrive fp32 or bf16; round-3 proved fp32 here).
// fp32: even u16 halves decode as bf16 with huge exponents ~22% of the time.
// flag: 0 = fp32, 1 = bf16.
// ---------------------------------------------------------------------------
__global__ void detect_dtype(const u16t* __restrict__ x, int* __restrict__ flag) {
  const int i = threadIdx.x;                 // 64 threads, 1 block
  const u16t u = x[i * 2];
  int hit = (((u >> 7) & 0xFF) >= 200) ? 1 : 0;
  #pragma unroll
  for (int m = 1; m < 64; m <<= 1) hit += __shfl_xor(hit, m, 64);
  if (i == 0) *flag = (hit >= 4) ? 0 : 1;
}

// Load 8 consecutive elements (bf16 or fp32 per isbf) as a bf16x8 fragment.
DEVINL bf16x8 load8_dyn(const char* base, size_t idx, int isbf) {
  if (isbf) return *(const bf16x8*)(base + idx * 2);
  const float* f = (const float*)(base + idx * 4);
  const float4 a = *(const float4*)f;
  const float4 b = *(const float4*)(f + 4);
  bf16x8 r;
  r[0] = (short)f2bf(a.x); r[1] = (short)f2bf(a.y);
  r[2] = (short)f2bf(a.z); r[3] = (short)f2bf(a.w);
  r[4] = (short)f2bf(b.x); r[5] = (short)f2bf(b.y);
  r[6] = (short)f2bf(b.z); r[7] = (short)f2bf(b.w);
  return r;
}

// ---------------------------------------------------------------------------
// C[m,n] = sum_k A[m,k]*B[n,k].  A:[M,K], B:[N,K] row-major.
// MODE 0: C row-major [M,N], fp32 if *flagp==0 else bf16 (final projection).
// MODE 1 (QKV): z∈{0,1}: head-split bf16 C[((b*16+h)*2048+t)*64+d];
//               z==2 (V): TRANSPOSED per head C[((b*16+h)*64+d)*2048+t],
//               ushort4-vectorized over the 4 consecutive-t accumulator regs.
// ---------------------------------------------------------------------------
template <int MODE, bool ADYN, bool BDYN>
__global__ __launch_bounds__(256) void gemm_bt(
    const void* __restrict__ A,
    const void* __restrict__ B0, const void* __restrict__ B1, const void* __restrict__ B2,
    void* __restrict__ C0, void* __restrict__ C1, void* __restrict__ C2,
    int M, int N, int K, const int* __restrict__ flagp) {
  __shared__ u16t As[128 * 32];
  __shared__ u16t Bs[128 * 32];

  const void* B = B0;
  void* C = C0;
  if (blockIdx.z == 1) { B = B1; C = C1; }
  else if (blockIdx.z == 2) { B = B2; C = C2; }

  const int fl = *flagp;              // 1 = inputs bf16, 0 = inputs fp32
  const int abf = ADYN ? fl : 1;
  const int bbf = BDYN ? fl : 1;

  const int tid = threadIdx.x;
  const int lane = tid & 63;
  const int w = tid >> 6;
  const int wm = w >> 1, wn = w & 1;
  const int quad = lane >> 4, cl = lane & 15;
  const int m0 = blockIdx.y * 128;
  const int n0 = blockIdx.x * 128;

  f32x4 acc[4][4] = {};

  for (int k0 = 0; k0 < K; k0 += 32) {
    __syncthreads();
    bf16x8 va[2], vb[2];
    int rowv[2], colv[2];
    #pragma unroll
    for (int i = 0; i < 2; ++i) {
      const int e = i * 256 + tid;   // 0..511 8-elem chunks (128 rows x 4 chunks)
      rowv[i] = e >> 2;
      colv[i] = (e & 3) * 8;
      va[i] = load8_dyn((const char*)A, (size_t)(m0 + rowv[i]) * K + k0 + colv[i], abf);
      vb[i] = load8_dyn((const char*)B, (size_t)(n0 + rowv[i]) * K + k0 + colv[i], bbf);
    }
    #pragma unroll
    for (int i = 0; i < 2; ++i) {
      *(bf16x8*)&As[rowv[i] * 32 + colv[i]] = va[i];
      *(bf16x8*)&Bs[rowv[i] * 32 + colv[i]] = vb[i];
    }
    __syncthreads();
    bf16x8 af[4], bfr[4];
    #pragma unroll
    for (int i = 0; i < 4; ++i)
      af[i] = *(const bf16x8*)&As[(wm * 64 + i * 16 + cl) * 32 + quad * 8];
    #pragma unroll
    for (int j = 0; j < 4; ++j)
      bfr[j] = *(const bf16x8*)&Bs[(wn * 64 + j * 16 + cl) * 32 + quad * 8];
    #pragma unroll
    for (int i = 0; i < 4; ++i)
      #pragma unroll
      for (int j = 0; j < 4; ++j)
        acc[i][j] = __builtin_amdgcn_mfma_f32_16x16x32_bf16(af[i], bfr[j], acc[i][j], 0, 0, 0);
  }

  #pragma unroll
  for (int i = 0; i < 4; ++i)
    #pragma unroll
    for (int j = 0; j < 4; ++j) {
      if (MODE == 1 && blockIdx.z == 2) {
        // V: transposed head-split store, 4 consecutive t per register quad
        const int mb = m0 + wm * 64 + i * 16 + quad * 4;   // t base (4 consecutive)
        const int n  = n0 + wn * 64 + j * 16 + cl;
        const int b = mb >> 11, t = mb & 2047, h = n >> 6, d = n & 63;
        ushort4 v4;
        v4.x = f2bf(acc[i][j][0]); v4.y = f2bf(acc[i][j][1]);
        v4.z = f2bf(acc[i][j][2]); v4.w = f2bf(acc[i][j][3]);
        *(ushort4*)&((u16t*)C)[(((size_t)(b * 16 + h)) * 64 + d) * 2048 + t] = v4;
      } else {
        #pragma unroll
        for (int r = 0; r < 4; ++r) {
          const int m = m0 + wm * 64 + i * 16 + quad * 4 + r;  // C/D: row=quad*4+reg
          const int n = n0 + wn * 64 + j * 16 + cl;            //      col=lane&15
          const float v = acc[i][j][r];
          if (MODE == 0) {
            if (fl) ((u16t*)C)[(size_t)m * N + n] = f2bf(v);
            else    ((float*)C)[(size_t)m * N + n] = v;
          } else {
            const int b = m >> 11, t = m & 2047, h = n >> 6, d = n & 63;
            ((u16t*)C)[(((size_t)(b * 16 + h)) * 2048 + t) * 64 + d] = f2bf(v);
          }
        }
      }
    }
}

// ---------------------------------------------------------------------------
// Flash attention. Grid: (32 q-tiles, 32 bh) = 1024 blocks = exactly 4/CU.
// Block 256 = 4 waves; wave owns 16 q-rows.
// Q,K: [bh][2048][64] bf16.  Vt: [bh][64][2048] bf16 (pre-transposed).
// Y out: token-major [4096][1024] bf16.
// LDS 35 KB: P-scratch ALIASES Ks (barrier-separated) -> 4 blocks/CU.
// ---------------------------------------------------------------------------
__global__ __launch_bounds__(256) void flash_attn(
    const u16t* __restrict__ Q, const u16t* __restrict__ K,
    const u16t* __restrict__ Vt, u16t* __restrict__ Y) {
  __shared__ u16t Ks[128 * 72];       // K-tile rows padded 64->72; P aliases [0,8704)
  __shared__ u16t Vs[64 * 136];       // V^T tile: Vs[d][j], j padded 128->136

  const int tid = threadIdx.x;
  const int lane = tid & 63;
  const int w = tid >> 6;
  const int quad = lane >> 4, cl = lane & 15;
  const int bh = blockIdx.y;
  const int q0 = blockIdx.x * 64;
  const size_t base = (size_t)bh * 2048 * 64;

  // Q A-fragments are tile-invariant: registers (A[m=lane&15][k=quad*8+j])
  bf16x8 aq[2];
  #pragma unroll
  for (int ks = 0; ks < 2; ++ks)
    aq[ks] = *(const bf16x8*)&Q[base + (size_t)(q0 + w * 16 + cl) * 64 + ks * 32 + quad * 8];

  f32x4 o[4] = {};                    // O acc (C-layout): row=quad*4+r, col=ds*16+cl
  float mrow[4], lrow[4];
  #pragma unroll
  for (int r = 0; r < 4; ++r) { mrow[r] = -1e30f; lrow[r] = 0.f; }

  u16t* Pw = &Ks[w * 16 * 136];       // per-wave P scratch, aliases Ks

  for (int j0 = 0; j0 < 2048; j0 += 128) {
    __syncthreads();                  // previous tile's P/Vs reads complete
    #pragma unroll
    for (int i = 0; i < 4; ++i) {     // K tile: 1024 float4 chunks
      const int idx = i * 256 + tid;
      const int r = idx >> 3, c = idx & 7;
      *(float4*)&Ks[r * 72 + c * 8] = *(const float4*)&K[base + (size_t)(j0 + r) * 64 + c * 8];
    }
    #pragma unroll
    for (int i = 0; i < 4; ++i) {     // V^T tile: 1024 float4 chunks, coalesced
      const int idx = i * 256 + tid;
      const int d = idx >> 4, jc = idx & 15;
      *(float4*)&Vs[d * 136 + jc * 8] =
          *(const float4*)&Vt[base + (size_t)d * 2048 + j0 + jc * 8];
    }
    __syncthreads();

    // S = Q K^T, *1/sqrt(64)
    f32x4 s[8] = {};
    #pragma unroll
    for (int ks = 0; ks < 2; ++ks)
      #pragma unroll
      for (int js = 0; js < 8; ++js) {
        const bf16x8 bk = *(const bf16x8*)&Ks[(js * 16 + cl) * 72 + ks * 32 + quad * 8];
        s[js] = __builtin_amdgcn_mfma_f32_16x16x32_bf16(aq[ks], bk, s[js], 0, 0, 0);
      }
    #pragma unroll
    for (int js = 0; js < 8; ++js)
      #pragma unroll
      for (int r = 0; r < 4; ++r) s[js][r] *= 0.125f;

    __syncthreads();                  // ALL waves done reading Ks -> safe to alias as P

    // online softmax; row (quad*4+r) owned by the 16 consecutive lanes of quad
    float mnew[4], alpha[4];
    #pragma unroll
    for (int r = 0; r < 4; ++r) {
      float v = s[0][r];
      #pragma unroll
      for (int js = 1; js < 8; ++js) v = fmaxf(v, s[js][r]);
      #pragma unroll
      for (int msk = 1; msk < 16; msk <<= 1) v = fmaxf(v, __shfl_xor(v, msk, 64));
      mnew[r] = fmaxf(mrow[r], v);
      alpha[r] = __expf(mrow[r] - mnew[r]);
      mrow[r] = mnew[r];
    }
    float rsum[4] = {0.f, 0.f, 0.f, 0.f};
    #pragma unroll
    for (int js = 0; js < 8; ++js)
      #pragma unroll
      for (int r = 0; r < 4; ++r) {
        const float p = __expf(s[js][r] - mnew[r]);
        rsum[r] += p;
        Pw[(quad * 4 + r) * 136 + js * 16 + cl] = f2bf(p);   // C-layout scatter
      }
    #pragma unroll
    for (int r = 0; r < 4; ++r) {
      float v = rsum[r];
      #pragma unroll
      for (int msk = 1; msk < 16; msk <<= 1) v += __shfl_xor(v, msk, 64);
      lrow[r] = lrow[r] * alpha[r] + v;
      #pragma unroll
      for (int ds = 0; ds < 4; ++ds) o[ds][r] *= alpha[r];
    }
    // Pw is wave-private: same-wave LDS write->read ordered by lgkmcnt

    // O += P @ V  (A=P[m=cl][k=j], B=Vs[n=d][k=j]; 4 k-steps x 4 d-subtiles)
    #pragma unroll
    for (int ks = 0; ks < 4; ++ks) {
      const bf16x8 ap = *(const bf16x8*)&Pw[cl * 136 + ks * 32 + quad * 8];
      #pragma unroll
      for (int ds = 0; ds < 4; ++ds) {
        const bf16x8 bv = *(const bf16x8*)&Vs[(ds * 16 + cl) * 136 + ks * 32 + quad * 8];
        o[ds] = __builtin_amdgcn_mfma_f32_16x16x32_bf16(ap, bv, o[ds], 0, 0, 0);
      }
    }
  }

  const int b = bh >> 4, h = bh & 15;
  #pragma unroll
  for (int ds = 0; ds < 4; ++ds)
    #pragma unroll
    for (int r = 0; r < 4; ++r) {
      const int t = q0 + w * 16 + quad * 4 + r;
      const int d = ds * 16 + cl;
      Y[((size_t)b * 2048 + t) * 1024 + h * 64 + d] = f2bf(o[ds][r] / lrow[r]);
    }
}

extern "C" void kernel_launch(void* const* d_in, const int* in_sizes, int n_in,
                              void* d_out, int out_size, void* d_ws, size_t ws_size,
                              hipStream_t stream) {
  (void)in_sizes; (void)n_in; (void)out_size; (void)ws_size;
  const void* x  = d_in[0];
  const void* Wq = d_in[1];
  const void* Wk = d_in[2];
  const void* Wv = d_in[3];
  const void* Wo = d_in[4];

  char* ws = (char*)d_ws;
  int*  flag = (int*)ws;                                   // dtype flag
  u16t* Qw  = (u16t*)(ws + (size_t)1  * 1024 * 1024);      // [32][2048][64] bf16
  u16t* Kw  = (u16t*)(ws + (size_t)9  * 1024 * 1024);      // [32][2048][64] bf16
  u16t* Vtw = (u16t*)(ws + (size_t)17 * 1024 * 1024);      // [32][64][2048] bf16 (transposed)
  u16t* Yw  = (u16t*)(ws + (size_t)25 * 1024 * 1024);      // [4096][1024] bf16

  detect_dtype<<<1, 64, 0, stream>>>((const u16t*)x, flag);
  // Q/K/V = x @ W^T; z selects weight; V stored transposed per head
  gemm_bt<1, true, true><<<dim3(8, 32, 3), 256, 0, stream>>>(
      x, Wq, Wk, Wv, Qw, Kw, Vtw, 4096, 1024, 1024, flag);
  // fused softmax(QK^T/8) V
  flash_attn<<<dim3(32, 32), 256, 0, stream>>>(Qw, Kw, Vtw, Yw);
  // out = Y @ Wo^T   (A = Yw always bf16; B/out dtype follow flag)
  gemm_bt<0, false, true><<<dim3(8, 32, 1), 256, 0, stream>>>(
      Yw, Wo, Wo, Wo, d_out, d_out, d_out, 4096, 1024, 1024, flag);
}